// Round 4
// baseline (223.978 us; speedup 1.0000x reference)
//
#include <hip/hip_runtime.h>
#include <stdint.h>

#define B_DIM 4
#define T_DIM 2048
#define C_DIM 1024
#define H_DIM 16
#define D_DIM 64
#define M_DIM (B_DIM * T_DIM)   // 8192
// 1/sqrt(D) * log2(e): QK^T lands in exp2 domain
#define QK_SCALE 0.18033688011112042f

typedef float f32x4 __attribute__((ext_vector_type(4)));
typedef float f32x16 __attribute__((ext_vector_type(16)));
typedef short bf16x8 __attribute__((ext_vector_type(8)));
typedef unsigned short u16;
typedef u16 u16x8 __attribute__((ext_vector_type(8)));

// single-instruction RNE f32->bf16 (low 16 bits of dest)
static __device__ __forceinline__ u16 f2b(float f) {
  uint32_t r;
  asm("v_cvt_pk_bf16_f32 %0, %1, %1" : "=v"(r) : "v"(f));
  return (u16)r;
}
// pack 2 f32 -> u32 of 2 bf16 (lo=a, hi=b)
static __device__ __forceinline__ uint32_t f2b2(float a, float b) {
  uint32_t r;
  asm("v_cvt_pk_bf16_f32 %0, %1, %2" : "=v"(r) : "v"(a), "v"(b));
  return r;
}

static __device__ __forceinline__ void gl_lds16(const u16* g, u16* l) {
  __builtin_amdgcn_global_load_lds(
      (const __attribute__((address_space(1))) void*)g,
      (__attribute__((address_space(3))) void*)l, 16, 0, 0);
}

// ---------------- f32 -> bf16 converts ----------------
__global__ void k_cvt(const float* __restrict__ src, u16* __restrict__ dst, int n4) {
  int i = blockIdx.x * blockDim.x + threadIdx.x;
  if (i < n4) {
    float4 v = ((const float4*)src)[i];
    uint2 o;
    o.x = f2b2(v.x, v.y);
    o.y = f2b2(v.z, v.w);
    ((uint2*)dst)[i] = o;
  }
}

// all four weight matrices in one dispatch; each is C*C floats = 2^18 float4
__global__ void k_cvtw(const float* __restrict__ s0, const float* __restrict__ s1,
                       const float* __restrict__ s2, const float* __restrict__ s3,
                       u16* __restrict__ d0, u16* __restrict__ d1,
                       u16* __restrict__ d2, u16* __restrict__ d3) {
  int i = blockIdx.x * blockDim.x + threadIdx.x;
  int seg = i >> 18;
  int j = i & ((1 << 18) - 1);
  const float* s = seg == 0 ? s0 : seg == 1 ? s1 : seg == 2 ? s2 : s3;
  u16* d = seg == 0 ? d0 : seg == 1 ? d1 : seg == 2 ? d2 : d3;
  float4 v = ((const float4*)s)[j];
  uint2 o;
  o.x = f2b2(v.x, v.y);
  o.y = f2b2(v.z, v.w);
  ((uint2*)d)[j] = o;
}

// ---------------- fused QKV GEMM, 256x256 tile, 8-wave, 4-phase/K-tile ------
// A [M][K] bf16, weights [C][K] bf16. Output split-head bf16 [B,H,T,D];
// Q gets QK_SCALE. grid = 384 blocks (32 rowblk x 12 colblk, colblk/4 = seg).
// LDS: [2 dbuf][2 khalf][256 rows][32 cols] per operand = 128 KiB total.
// Per phase: stage 1 half-tile of t+1; ds_read frag subtile; barrier;
// lgkmcnt(0); setprio(1); 16 MFMA; setprio(0); [vmcnt(4) phases 1,3]; barrier.
#define NT 16
__global__ __launch_bounds__(512, 2) void k_gemm_qkv(
    const u16* __restrict__ A,
    const u16* __restrict__ w0, const u16* __restrict__ w1, const u16* __restrict__ w2,
    const float* __restrict__ b0, const float* __restrict__ b1, const float* __restrict__ b2,
    u16* __restrict__ Qo, u16* __restrict__ Ko, u16* __restrict__ Vo) {
  __shared__ u16 LA[2][2][256 * 32];
  __shared__ u16 LB[2][2][256 * 32];
  const int tid = threadIdx.x;
  const int l = tid & 63;
  const int w = tid >> 6;
  const int wm = w >> 2, wn = w & 3;           // 2M x 4N wave grid
  const int lrow = l & 15, lk = l >> 4;
  const int K = C_DIM;

  // XCD-bijective swizzle: 384 blocks = 8 XCDs x 48
  const int bid = blockIdx.x;
  const int swz = (bid & 7) * 48 + (bid >> 3);
  const int rowblk = swz / 12, colblk = swz % 12;
  const int seg = colblk >> 2;
  const int brow = rowblk * 256, bcol = (colblk & 3) * 256;

  const u16* Bw = seg == 0 ? w0 : seg == 1 ? w1 : w2;
  const float* bias = seg == 0 ? b0 : seg == 1 ? b1 : b2;
  u16* Out = seg == 0 ? Qo : seg == 1 ? Ko : Vo;
  const float scale = seg == 0 ? QK_SCALE : 1.f;

  // staging coords: instr0 -> rows 0..127, instr1 -> rows 128..255 of the tile
  const int sr0 = tid >> 2, sc0 = (tid & 3) * 8;
  const int sr1 = (tid + 512) >> 2;

#define STA(db, kh, t)                                                              \
  {                                                                                 \
    gl_lds16(A + (size_t)(brow + sr0) * K + (t) * 64 + (kh) * 32 + sc0,             \
             &LA[db][kh][sr0 * 32 + sc0]);                                          \
    gl_lds16(A + (size_t)(brow + sr1) * K + (t) * 64 + (kh) * 32 + sc0,             \
             &LA[db][kh][sr1 * 32 + sc0]);                                          \
  }
#define STB(db, kh, t)                                                              \
  {                                                                                 \
    gl_lds16(Bw + (size_t)(bcol + sr0) * K + (t) * 64 + (kh) * 32 + sc0,            \
             &LB[db][kh][sr0 * 32 + sc0]);                                          \
    gl_lds16(Bw + (size_t)(bcol + sr1) * K + (t) * 64 + (kh) * 32 + sc0,            \
             &LB[db][kh][sr1 * 32 + sc0]);                                          \
  }
#define LDA_(f, kh, db) (*(const bf16x8*)(&LA[db][kh][(wm * 128 + (f) * 16 + lrow) * 32 + lk * 8]))
#define LDB_(g, kh, db) (*(const bf16x8*)(&LB[db][kh][(wn * 64 + (g) * 16 + lrow) * 32 + lk * 8]))

  f32x4 acc[8][4];
#pragma unroll
  for (int f = 0; f < 8; ++f)
#pragma unroll
    for (int g = 0; g < 4; ++g) acc[f][g] = (f32x4){0.f, 0.f, 0.f, 0.f};

  // prologue: tile 0 fully staged into dbuf 0
  STA(0, 0, 0); STB(0, 0, 0); STA(0, 1, 0); STB(0, 1, 0);
  asm volatile("s_waitcnt vmcnt(0)" ::: "memory");
  __syncthreads();

  for (int t = 0; t < NT; ++t) {
    const int db = t & 1, ndb = db ^ 1;
    const bool pf = (t + 1 < NT);
    bf16x8 afr[4], bfr[4];

    // ---- phase 0: kh=0, frags 0-3; stage A(t+1, k0) ----
    if (pf) STA(ndb, 0, t + 1);
#pragma unroll
    for (int g = 0; g < 4; ++g) bfr[g] = LDB_(g, 0, db);
#pragma unroll
    for (int j = 0; j < 4; ++j) afr[j] = LDA_(j, 0, db);
    __builtin_amdgcn_s_barrier();
    asm volatile("s_waitcnt lgkmcnt(0)" ::: "memory");
    __builtin_amdgcn_sched_barrier(0);
    __builtin_amdgcn_s_setprio(1);
#pragma unroll
    for (int j = 0; j < 4; ++j)
#pragma unroll
      for (int g = 0; g < 4; ++g)
        acc[j][g] = __builtin_amdgcn_mfma_f32_16x16x32_bf16(afr[j], bfr[g], acc[j][g], 0, 0, 0);
    __builtin_amdgcn_s_setprio(0);
    __builtin_amdgcn_s_barrier();

    // ---- phase 1: kh=0, frags 4-7; stage B(t+1, k0) ----
    if (pf) STB(ndb, 0, t + 1);
#pragma unroll
    for (int j = 0; j < 4; ++j) afr[j] = LDA_(4 + j, 0, db);
    __builtin_amdgcn_s_barrier();
    asm volatile("s_waitcnt lgkmcnt(0)" ::: "memory");
    __builtin_amdgcn_sched_barrier(0);
    __builtin_amdgcn_s_setprio(1);
#pragma unroll
    for (int j = 0; j < 4; ++j)
#pragma unroll
      for (int g = 0; g < 4; ++g)
        acc[4 + j][g] = __builtin_amdgcn_mfma_f32_16x16x32_bf16(afr[j], bfr[g], acc[4 + j][g], 0, 0, 0);
    __builtin_amdgcn_s_setprio(0);
    if (t == NT - 1) {
      asm volatile("s_waitcnt vmcnt(0)" ::: "memory");
    } else {
      asm volatile("s_waitcnt vmcnt(4)" ::: "memory");
    }
    __builtin_amdgcn_s_barrier();

    // ---- phase 2: kh=1, frags 0-3; stage A(t+1, k1) ----
    if (pf) STA(ndb, 1, t + 1);
#pragma unroll
    for (int g = 0; g < 4; ++g) bfr[g] = LDB_(g, 1, db);
#pragma unroll
    for (int j = 0; j < 4; ++j) afr[j] = LDA_(j, 1, db);
    __builtin_amdgcn_s_barrier();
    asm volatile("s_waitcnt lgkmcnt(0)" ::: "memory");
    __builtin_amdgcn_sched_barrier(0);
    __builtin_amdgcn_s_setprio(1);
#pragma unroll
    for (int j = 0; j < 4; ++j)
#pragma unroll
      for (int g = 0; g < 4; ++g)
        acc[j][g] = __builtin_amdgcn_mfma_f32_16x16x32_bf16(afr[j], bfr[g], acc[j][g], 0, 0, 0);
    __builtin_amdgcn_s_setprio(0);
    __builtin_amdgcn_s_barrier();

    // ---- phase 3: kh=1, frags 4-7; stage B(t+1, k1) ----
    if (pf) STB(ndb, 1, t + 1);
#pragma unroll
    for (int j = 0; j < 4; ++j) afr[j] = LDA_(4 + j, 1, db);
    __builtin_amdgcn_s_barrier();
    asm volatile("s_waitcnt lgkmcnt(0)" ::: "memory");
    __builtin_amdgcn_sched_barrier(0);
    __builtin_amdgcn_s_setprio(1);
#pragma unroll
    for (int j = 0; j < 4; ++j)
#pragma unroll
      for (int g = 0; g < 4; ++g)
        acc[4 + j][g] = __builtin_amdgcn_mfma_f32_16x16x32_bf16(afr[j], bfr[g], acc[4 + j][g], 0, 0, 0);
    __builtin_amdgcn_s_setprio(0);
    asm volatile("s_waitcnt vmcnt(4)" ::: "memory");
    __builtin_amdgcn_s_barrier();
  }

  // ---- epilogue: split-head scatter ----
#pragma unroll
  for (int f = 0; f < 8; ++f) {
    int rg0 = brow + wm * 128 + f * 16 + lk * 4;
#pragma unroll
    for (int g = 0; g < 4; ++g) {
      int cg = bcol + wn * 64 + g * 16 + lrow;
      float bv = bias[cg];
#pragma unroll
      for (int i = 0; i < 4; ++i) {
        int rg = rg0 + i;
        float val = (acc[f][g][i] + bv) * scale;
        int bb = rg >> 11, tt = rg & (T_DIM - 1);
        int hh = cg >> 6, dd = cg & 63;
        Out[(((size_t)bb * H_DIM + hh) * T_DIM + tt) * D_DIM + dd] = f2b(val);
      }
    }
  }
#undef STA
#undef STB
#undef LDA_
#undef LDB_
}

// ---------------- output projection GEMM: out = A @ W^T + b (f32 out) --------
__global__ __launch_bounds__(256) void k_gemm_proj(
    const u16* __restrict__ A, const u16* __restrict__ Bw,
    const float* __restrict__ bias, float* __restrict__ Cout) {
  __shared__ u16 As[128 * 32];
  __shared__ u16 Bs[128 * 32];
  const int tid = threadIdx.x;
  const int l = tid & 63;
  const int w = tid >> 6;
  const int wr = w >> 1, wc = w & 1;
  const int brow = blockIdx.y * 128, bcol = blockIdx.x * 128;
  const int lrow = l & 15, lk = l >> 4;
  const int K = C_DIM, N = C_DIM;

  f32x4 acc[4][4];
  for (int m = 0; m < 4; ++m)
    for (int n = 0; n < 4; ++n)
      acc[m][n] = (f32x4){0.f, 0.f, 0.f, 0.f};

  for (int kt = 0; kt < K; kt += 32) {
    __syncthreads();
    {
      int slot = tid;
      int r0 = slot >> 2, c0 = slot & 3;
      gl_lds16(A + (size_t)(brow + r0) * K + kt + c0 * 8, As + slot * 8);
      gl_lds16(Bw + (size_t)(bcol + r0) * K + kt + c0 * 8, Bs + slot * 8);
      int slot2 = slot + 256;
      int r1 = slot2 >> 2, c1 = slot2 & 3;
      gl_lds16(A + (size_t)(brow + r1) * K + kt + c1 * 8, As + slot2 * 8);
      gl_lds16(Bw + (size_t)(bcol + r1) * K + kt + c1 * 8, Bs + slot2 * 8);
    }
    asm volatile("s_waitcnt vmcnt(0)" ::: "memory");
    __syncthreads();

    bf16x8 af[4], bfr[4];
#pragma unroll
    for (int m = 0; m < 4; ++m)
      af[m] = *(const bf16x8*)(As + (wr * 64 + m * 16 + lrow) * 32 + lk * 8);
#pragma unroll
    for (int n = 0; n < 4; ++n)
      bfr[n] = *(const bf16x8*)(Bs + (wc * 64 + n * 16 + lrow) * 32 + lk * 8);
#pragma unroll
    for (int m = 0; m < 4; ++m) {
#pragma unroll
      for (int n = 0; n < 4; ++n)
        acc[m][n] = __builtin_amdgcn_mfma_f32_16x16x32_bf16(af[m], bfr[n], acc[m][n], 0, 0, 0);
    }
  }

#pragma unroll
  for (int m = 0; m < 4; ++m) {
    int rg0 = brow + wr * 64 + m * 16 + lk * 4;
#pragma unroll
    for (int n = 0; n < 4; ++n) {
      int cg = bcol + wc * 64 + n * 16 + lrow;
      float bv = bias[cg];
#pragma unroll
      for (int i = 0; i < 4; ++i)
        Cout[(size_t)(rg0 + i) * N + cg] = acc[m][n][i] + bv;
    }
  }
}

// ---------------- V transpose: [B,H,T,D] -> [B,H,D,T] ----------------
__global__ __launch_bounds__(256) void k_transpose(
    const u16* __restrict__ V, u16* __restrict__ Vt) {
  __shared__ u16 tile[64][65];
  const int tid = threadIdx.x;
  const int bh = blockIdx.y;
  const int t0 = blockIdx.x * 64;
  const size_t ibase = (size_t)bh * T_DIM * D_DIM + (size_t)t0 * D_DIM;
  const size_t obase = (size_t)bh * D_DIM * T_DIM + t0;

#pragma unroll
  for (int it = 0; it < 2; ++it) {
    int row = (tid >> 3) + it * 32;
    int blk = tid & 7;
    u16x8 v = *(const u16x8*)(V + ibase + (size_t)row * D_DIM + blk * 8);
#pragma unroll
    for (int j = 0; j < 8; ++j) tile[row][blk * 8 + j] = v[j];
  }
  __syncthreads();
#pragma unroll
  for (int it = 0; it < 2; ++it) {
    int d = (tid >> 3) + it * 32;
    int blk = tid & 7;
    u16x8 v;
#pragma unroll
    for (int j = 0; j < 8; ++j) v[j] = tile[blk * 8 + j][d];
    *(u16x8*)(Vt + obase + (size_t)d * T_DIM + blk * 8) = v;
  }
}

// ---------------- causal flash attention, swapped-operand in-register softmax ----
__global__ __launch_bounds__(256) void k_attn(
    const u16* __restrict__ Q, const u16* __restrict__ Kg,
    const u16* __restrict__ Vt, u16* __restrict__ O) {
  __shared__ u16 Ks[2][64 * 64];
  __shared__ u16 Vs[2][64 * 64];

  const int tid = threadIdx.x;
  const int l = tid & 63;
  const int w = tid >> 6;
  const int bh = blockIdx.x;
  const int qb = 15 - blockIdx.y;          // heavy blocks dispatch first
  const int q0 = qb * 128;
  const int ql = l & 31;                   // lane's q row (MFMA col)
  const int hi = l >> 5;
  const int r0 = q0 + w * 32;              // wave's first q row
  const int qg = r0 + ql;                  // lane's global q row

  const size_t qkbase = (size_t)bh * T_DIM * D_DIM;
  const size_t vtbase = (size_t)bh * D_DIM * T_DIM;

  const int sr0 = tid >> 3, sc = tid & 7;
  const int sr1 = (tid + 256) >> 3;
  const int kcol0 = (sc ^ (sr0 & 7)) * 8;
  const int kcol1 = (sc ^ (sr1 & 7)) * 8;

#define STAGE(buf, kt)                                                                   \
  {                                                                                      \
    gl_lds16(Kg + qkbase + (size_t)((kt) * 64 + sr0) * D_DIM + kcol0, Ks[buf] + tid * 8);\
    gl_lds16(Vt + vtbase + (size_t)sr0 * T_DIM + (kt) * 64 + kcol0, Vs[buf] + tid * 8);  \
    gl_lds16(Kg + qkbase + (size_t)((kt) * 64 + sr1) * D_DIM + kcol1,                    \
             Ks[buf] + (tid + 256) * 8);                                                 \
    gl_lds16(Vt + vtbase + (size_t)sr1 * T_DIM + (kt) * 64 + kcol1,                      \
             Vs[buf] + (tid + 256) * 8);                                                 \
  }

  bf16x8 qf[4];
#pragma unroll
  for (int kk = 0; kk < 4; ++kk)
    qf[kk] = *(const bf16x8*)(Q + qkbase + (size_t)qg * D_DIM + kk * 16 + hi * 8);

  f32x16 oacc[2];
#pragma unroll
  for (int dt = 0; dt < 2; ++dt)
#pragma unroll
    for (int r = 0; r < 16; ++r) oacc[dt][r] = 0.f;
  float m_run = -1e30f, l_run = 0.f;

  const int tdiag = r0 >> 6;
  const int nkt = (q0 >> 6) + 2;

  STAGE(0, 0);

  for (int kt = 0; kt < nkt; ++kt) {
    const int cur = kt & 1;
    if (kt + 1 < nkt) {
      STAGE(cur ^ 1, kt + 1);
      asm volatile("s_waitcnt vmcnt(4)" ::: "memory");
    } else {
      asm volatile("s_waitcnt vmcnt(0)" ::: "memory");
    }
    __syncthreads();

    if (kt <= tdiag) {
      f32x16 s[2];
#pragma unroll
      for (int a = 0; a < 2; ++a)
#pragma unroll
        for (int r = 0; r < 16; ++r) s[a][r] = 0.f;

#pragma unroll
      for (int kk = 0; kk < 4; ++kk) {
#pragma unroll
        for (int a = 0; a < 2; ++a) {
          int row = a * 32 + ql;
          int blk = (kk * 2 + hi) ^ (row & 7);
          bf16x8 kf = *(const bf16x8*)(Ks[cur] + row * 64 + blk * 8);
          s[a] = __builtin_amdgcn_mfma_f32_32x32x16_bf16(kf, qf[kk], s[a], 0, 0, 0);
        }
      }

      if (kt == tdiag) {
#pragma unroll
        for (int a = 0; a < 2; ++a) {
#pragma unroll
          for (int r = 0; r < 16; ++r) {
            int kv = kt * 64 + a * 32 + (r & 3) + 8 * (r >> 2) + 4 * hi;
            if (kv > qg) s[a][r] = -1e30f;
          }
        }
      }

      float t[16];
#pragma unroll
      for (int r = 0; r < 16; ++r) t[r] = fmaxf(s[0][r], s[1][r]);
#pragma unroll
      for (int r = 0; r < 8; ++r) t[r] = fmaxf(t[r], t[r + 8]);
#pragma unroll
      for (int r = 0; r < 4; ++r) t[r] = fmaxf(t[r], t[r + 4]);
      float pm = fmaxf(fmaxf(t[0], t[1]), fmaxf(t[2], t[3]));
      pm = fmaxf(pm, __shfl_xor(pm, 32, 64));

      if (__any(pm > m_run + 8.f)) {
        float mn = fmaxf(m_run, pm);
        float sc_ = exp2f(m_run - mn);
        m_run = mn;
        l_run *= sc_;
#pragma unroll
        for (int dt = 0; dt < 2; ++dt)
#pragma unroll
          for (int r = 0; r < 16; ++r) oacc[dt][r] *= sc_;
      }

      float rs0 = 0.f, rs1 = 0.f, rs2 = 0.f, rs3 = 0.f;
#pragma unroll
      for (int a = 0; a < 2; ++a) {
#pragma unroll
        for (int r = 0; r < 16; ++r) {
          float p = exp2f(s[a][r] - m_run);
          s[a][r] = p;
          if ((r & 3) == 0) rs0 += p;
          else if ((r & 3) == 1) rs1 += p;
          else if ((r & 3) == 2) rs2 += p;
          else rs3 += p;
        }
      }
      float rs = (rs0 + rs1) + (rs2 + rs3);
      rs += __shfl_xor(rs, 32, 64);
      l_run += rs;

#pragma unroll
      for (int kk = 0; kk < 4; ++kk) {
        const int a = kk >> 1;
        const int base = (kk & 1) * 8;
        union { uint32_t wd[4]; bf16x8 v; } pf;
#pragma unroll
        for (int i = 0; i < 2; ++i) {
          uint32_t Aw = f2b2(s[a][base + 2 * i], s[a][base + 2 * i + 1]);
          uint32_t Bw = f2b2(s[a][base + 4 + 2 * i], s[a][base + 5 + 2 * i]);
          uint32_t As_ = (uint32_t)__shfl_xor((int)Aw, 32, 64);
          uint32_t Bs_ = (uint32_t)__shfl_xor((int)Bw, 32, 64);
          pf.wd[i] = hi ? Bs_ : Aw;
          pf.wd[2 + i] = hi ? Bw : As_;
        }
#pragma unroll
        for (int dt = 0; dt < 2; ++dt) {
          int row = dt * 32 + ql;
          int blk = (kk * 2 + hi) ^ (row & 7);
          bf16x8 vf = *(const bf16x8*)(Vs[cur] + row * 64 + blk * 8);
          oacc[dt] = __builtin_amdgcn_mfma_f32_32x32x16_bf16(vf, pf.v, oacc[dt], 0, 0, 0);
        }
      }
    }
    __syncthreads();
  }

  const int bb = bh >> 4, hh = bh & 15;
  const float inv = 1.f / l_run;
  u16* orow = O + ((size_t)bb * T_DIM + qg) * C_DIM + hh * D_DIM;
#pragma unroll
  for (int dt = 0; dt < 2; ++dt) {
#pragma unroll
    for (int g = 0; g < 4; ++g) {
      uint2 val;
      val.x = f2b2(oacc[dt][g * 4 + 0] * inv, oacc[dt][g * 4 + 1] * inv);
      val.y = f2b2(oacc[dt][g * 4 + 2] * inv, oacc[dt][g * 4 + 3] * inv);
      *(uint2*)(orow + dt * 32 + g * 8 + 4 * hi) = val;
    }
  }
}

// ---------------- host launcher ----------------
extern "C" void kernel_launch(void* const* d_in, const int* in_sizes, int n_in,
                              void* d_out, int out_size, void* d_ws, size_t ws_size,
                              hipStream_t stream) {
  (void)in_sizes; (void)n_in; (void)out_size; (void)ws_size;
  const float* x  = (const float*)d_in[0];
  const float* wq = (const float*)d_in[1];
  const float* bq = (const float*)d_in[2];
  const float* wk = (const float*)d_in[3];
  const float* bk = (const float*)d_in[4];
  const float* wv = (const float*)d_in[5];
  const float* bv = (const float*)d_in[6];
  const float* wo = (const float*)d_in[7];
  const float* bo = (const float*)d_in[8];
  float* out = (float*)d_out;

  u16* xb  = (u16*)d_ws;
  u16* wqb = xb + (size_t)M_DIM * C_DIM;
  u16* wkb = wqb + (size_t)C_DIM * C_DIM;
  u16* wvb = wkb + (size_t)C_DIM * C_DIM;
  u16* wob = wvb + (size_t)C_DIM * C_DIM;
  u16* Qb  = wob + (size_t)C_DIM * C_DIM;
  u16* Kb  = Qb + (size_t)M_DIM * C_DIM;
  u16* Vb  = Kb + (size_t)M_DIM * C_DIM;
  u16* Vtb = Vb + (size_t)M_DIM * C_DIM;
  u16* Ob  = Vb;  // alias: V consumed by k_transpose before k_attn writes O

  int n4x = M_DIM * C_DIM / 4;
  k_cvt<<<(n4x + 255) / 256, 256, 0, stream>>>(x, xb, n4x);
  k_cvtw<<<4096, 256, 0, stream>>>(wq, wk, wv, wo, wqb, wkb, wvb, wob);

  k_gemm_qkv<<<384, 512, 0, stream>>>(
      xb, wqb, wkb, wvb, bq, bk, bv, Qb, Kb, Vb);

  k_transpose<<<dim3(T_DIM / 64, B_DIM * H_DIM), 256, 0, stream>>>(Vb, Vtb);
  k_attn<<<dim3(B_DIM * H_DIM, 16), 256, 0, stream>>>(Qb, Kb, Vtb, Ob);
  k_gemm_proj<<<dim3(C_DIM / 128, M_DIM / 128), 256, 0, stream>>>(Ob, wob, bo, out);
}